// Round 14
// baseline (6308.367 us; speedup 1.0000x reference)
//
#include <hip/hip_runtime.h>
#include <cmath>

// ---------------------------------------------------------------------------
// ConvFrameDecoder — fp32, round 14.
// r13 baseline (5285us, absmax 9.77e-4). Two intra-block deltas:
// (1) visconv: W1T read from global (L2-resident, wave-broadcast) instead of
//     LDS staging — LDS was 1.9x oversubscribed (5 b128 per 64 FMA); now
//     1 b128 per 64 FMA -> VALU-bound. LDS drops to 34.8KB (Xc+Y1c alias).
// (2) fc: gates-style float4 staging (4-way instead of 8-way LDS write
//     conflicts, 1/4 the load instrs). Grid/swizzle unchanged.
// Everything else byte-identical to r13. No cross-workgroup sync anywhere.
// ---------------------------------------------------------------------------

#define NB   128
#define NT   25
#define NL   512
#define DH   1024
#define DF   512
#define DIN  1664
#define DCAT 2688
#define NV   512
#define NSEG 8
#define NGZ  12

// d_out offsets (floats): actions[128,25,512], scores[128,25,512,1], h, c
#define ACT_OFF 0
#define SC_OFF  1638400
#define H_OFF   3276800
#define C_OFF   3407872

// workspace offsets (floats); peak < 16,450,176 floats = 65.8 MB
#define WS_W1T   0u
#define WS_W2T   131072u
#define WS_APT   147456u
#define WS_EWT   491520u
#define WS_BSUM  557056u
#define WS_A1    561152u
#define WS_B1    561408u
#define WS_A2    561664u
#define WS_B2    561728u
#define WS_XCAT  561792u     // [128][2688] = [vis|weighted|e|h]
#define WS_CBUF  905856u     // [128][1024]
#define WS_QPART 1036928u    // [8][128][1024]; fc z=1 partial in setup
#define WS_VIS   4776576u    // [3200][512]
#define WS_Y2F   6414976u    // [3200][3136] — DEAD after fc; aliases below:
#define WS_ATT   6414976u    // [128][8][1032] (acc1024,m,z)
#define WS_ATTRAW 7471744u   // [128][512]
#define WS_GPART 7537280u    // [12][128][4096] -> ends 13828736

// ---------------------------------------------------------------------------
__global__ __launch_bounds__(256) void k_prep(
    const float* __restrict__ conv1_w, const float* __restrict__ conv1_b,
    const float* __restrict__ bn1_g, const float* __restrict__ bn1_b,
    const float* __restrict__ bn1_m, const float* __restrict__ bn1_v,
    const float* __restrict__ conv2_w, const float* __restrict__ conv2_b,
    const float* __restrict__ bn2_g, const float* __restrict__ bn2_b,
    const float* __restrict__ bn2_m, const float* __restrict__ bn2_v,
    const float* __restrict__ actor_w, const float* __restrict__ emb_w,
    const float* __restrict__ b_ih, const float* __restrict__ b_hh,
    float* __restrict__ ws)
{
  int i = blockIdx.x * 256 + threadIdx.x;
  if (i < 131072) {                      // W1T[c][o] = conv1_w[o][c]
    int c = i >> 8, o = i & 255;
    ws[WS_W1T + i] = conv1_w[o * 512 + c];
    return;
  }
  i -= 131072;
  if (i < 16384) {                       // W2T[c][o] = conv2_w[o][c]
    int c = i >> 6, o = i & 63;
    ws[WS_W2T + i] = conv2_w[o * 256 + c];
    return;
  }
  i -= 16384;
  if (i < 344064) {                      // APT[k][o], cont=[h|inp] -> xcat=[inp|h]
    int k = i >> 7, o = i & 127;
    int src = (k < DIN) ? (DH + k) : (k - DIN);
    ws[WS_APT + i] = actor_w[o * DCAT + src];
    return;
  }
  i -= 344064;
  if (i < 65536) {                       // EWT[j][v] = emb_w[v][j]
    int j = i >> 9, v = i & 511;
    ws[WS_EWT + i] = emb_w[v * 128 + j];
    return;
  }
  i -= 65536;
  if (i < 4096) { ws[WS_BSUM + i] = b_ih[i] + b_hh[i]; return; }
  i -= 4096;
  if (i < 256) {
    float a = bn1_g[i] / sqrtf(bn1_v[i] + 1e-5f);
    ws[WS_A1 + i] = a;
    ws[WS_B1 + i] = a * (conv1_b[i] - bn1_m[i]) + bn1_b[i];
    return;
  }
  i -= 256;
  if (i < 64) {
    float a = bn2_g[i] / sqrtf(bn2_v[i] + 1e-5f);
    ws[WS_A2 + i] = a;
    ws[WS_B2 + i] = a * (conv2_b[i] - bn2_m[i]) + bn2_b[i];
  }
}

// ---------------------------------------------------------------------------
__global__ __launch_bounds__(256) void k_init(
    const float* __restrict__ h0, const float* __restrict__ c0,
    const float* __restrict__ go, float* __restrict__ ws)
{
  int b = blockIdx.x, tid = threadIdx.x;
  if (tid < 128) ws[WS_XCAT + b * DCAT + 1536 + tid] = go[tid];
  for (int d = tid; d < 1024; d += 256) {
    ws[WS_XCAT + b * DCAT + 1664 + d] = h0[b * 1024 + d];
    ws[WS_CBUF + b * 1024 + d] = c0[b * 1024 + d];
  }
}

// ---------------------------------------------------------------------------
// visconv v4: W1T/W2T read from global (L2-resident); LDS only Xc + Y1c.
__global__ __launch_bounds__(256) void k_visconv(
    const float* __restrict__ frames, float* __restrict__ ws)
{
  __shared__ float lds[8704];            // 34.8KB: Xc[32][64] | later Y1c[128][68]
  float* Xc  = lds;
  float* Y1c = lds;
  const int bt = blockIdx.x, tid = threadIdx.x;
  const int tn = tid & 15, tm = tid >> 4;
  const float* img = frames + (size_t)bt * 25088;
  const float* W1T = ws + WS_W1T;
  const float* W2T = ws + WS_W2T;

  float acc1[4][16];
  #pragma unroll
  for (int m = 0; m < 4; ++m)
    #pragma unroll
    for (int j = 0; j < 16; ++j) acc1[m][j] = 0.f;

  for (int i = tid; i < 2048; i += 256) Xc[i] = 0.f;   // zero pads hw 49..63
  __syncthreads();

  for (int ch = 0; ch < 16; ++ch) {
    for (int i4 = tid; i4 < 392; i4 += 256) {
      float4 v = *(const float4*)(img + ch * 1568 + (i4 << 2));
      int gi = i4 << 2;
      #pragma unroll
      for (int j = 0; j < 4; ++j) {
        int e = gi + j, c = e / 49, hw = e - c * 49;
        Xc[(c << 6) + hw] = (&v.x)[j];
      }
    }
    __syncthreads();
    const float* Wg = W1T + (ch << 13);  // [32][256] chunk, from L2
    #pragma unroll 4
    for (int c = 0; c < 32; ++c) {
      const float4 a4 = *(const float4*)&Xc[(c << 6) + (tm << 2)];
      float a[4] = {a4.x, a4.y, a4.z, a4.w};
      const float* wr = &Wg[(c << 8) + (tn << 2)];
      #pragma unroll
      for (int ko = 0; ko < 4; ++ko) {
        const float4 b4 = *(const float4*)&wr[ko << 6];
        float bb[4] = {b4.x, b4.y, b4.z, b4.w};
        #pragma unroll
        for (int m = 0; m < 4; ++m)
          #pragma unroll
          for (int jo = 0; jo < 4; ++jo)
            acc1[m][(ko << 2) + jo] += a[m] * bb[jo];
      }
    }
    __syncthreads();
  }

  // bn1 + relu in registers
  #pragma unroll
  for (int ko = 0; ko < 4; ++ko)
    #pragma unroll
    for (int jo = 0; jo < 4; ++jo) {
      const int o = (ko << 6) + (tn << 2) + jo;
      const float aa = ws[WS_A1 + o], bb = ws[WS_B1 + o];
      #pragma unroll
      for (int m = 0; m < 4; ++m)
        acc1[m][(ko << 2) + jo] = fmaxf(aa * acc1[m][(ko << 2) + jo] + bb, 0.f);
    }

  // conv2: two 128-channel rounds through Y1c (LDS alias); W2T from global
  float acc2[4][4];
  #pragma unroll
  for (int m = 0; m < 4; ++m)
    #pragma unroll
    for (int j = 0; j < 4; ++j) acc2[m][j] = 0.f;
  for (int r = 0; r < 2; ++r) {
    __syncthreads();
    #pragma unroll
    for (int kh = 0; kh < 2; ++kh) {
      const int ko = (r << 1) + kh;
      #pragma unroll
      for (int jo = 0; jo < 4; ++jo) {
        const int row = (kh << 6) + (tn << 2) + jo;
        float4 v;
        v.x = acc1[0][(ko << 2) + jo]; v.y = acc1[1][(ko << 2) + jo];
        v.z = acc1[2][(ko << 2) + jo]; v.w = acc1[3][(ko << 2) + jo];
        *(float4*)&Y1c[row * 68 + (tm << 2)] = v;
      }
    }
    __syncthreads();
    #pragma unroll 4
    for (int c2l = 0; c2l < 128; ++c2l) {
      const float4 a4 = *(const float4*)&Y1c[c2l * 68 + (tm << 2)];
      float a[4] = {a4.x, a4.y, a4.z, a4.w};
      const float4 b4 = *(const float4*)&W2T[(((r << 7) + c2l) << 6) + (tn << 2)];
      float bb[4] = {b4.x, b4.y, b4.z, b4.w};
      #pragma unroll
      for (int m = 0; m < 4; ++m)
        #pragma unroll
        for (int jo = 0; jo < 4; ++jo)
          acc2[m][jo] += a[m] * bb[jo];
    }
  }

  float* y2f = ws + WS_Y2F + (size_t)bt * 3136;
  #pragma unroll
  for (int jo = 0; jo < 4; ++jo) {
    const int o2 = (tn << 2) + jo;
    const float aa = ws[WS_A2 + o2], bb = ws[WS_B2 + o2];
    #pragma unroll
    for (int m = 0; m < 4; ++m) {
      const int hw = (tm << 2) + m;
      if (hw < 49) y2f[o2 * 49 + hw] = fmaxf(aa * acc2[m][jo] + bb, 0.f);
    }
  }
}

// ---------------------------------------------------------------------------
// fc GEMM, 64x64 tiles, XCD-swizzled, float4 staging (4-way conflicts max).
// grid (400, 2): w=(fid&7)*50+(fid>>3); bm=w>>3, bn=w&7; bz = K-half.
__global__ __launch_bounds__(256) void k_gemmfc(
    const float* __restrict__ A, const float* __restrict__ B,
    float* __restrict__ ws)
{
  __shared__ float As[32 * 68];
  __shared__ float Bs[32 * 68];
  const int tid = threadIdx.x;
  const int fid = blockIdx.x, bz = blockIdx.y;
  const int w = (fid & 7) * 50 + (fid >> 3);
  const int bm = w >> 3, bn = w & 7;
  const int tm = tid >> 4, tn = tid & 15;
  float acc[4][4];
  #pragma unroll
  for (int i = 0; i < 4; ++i)
    #pragma unroll
    for (int j = 0; j < 4; ++j) acc[i][j] = 0.f;

  const int kbase0 = bz * 1568;
  for (int kk = 0; kk < 1568; kk += 32) {
    const int kb = kbase0 + kk;
    #pragma unroll
    for (int i = 0; i < 2; ++i) {        // 512 float4 for As+Bs each? no: 64rx8kq=512 total/side/2
      const int e = tid + i * 256;       // e in [0,512): r=e>>3 (0..63), kq=e&7
      const int r = e >> 3, kq = e & 7;
      const float4 av = *(const float4*)&A[(size_t)(bm * 64 + r) * 3136 + kb + kq * 4];
      As[(kq * 4 + 0) * 68 + r] = av.x;
      As[(kq * 4 + 1) * 68 + r] = av.y;
      As[(kq * 4 + 2) * 68 + r] = av.z;
      As[(kq * 4 + 3) * 68 + r] = av.w;
      const float4 bv = *(const float4*)&B[(size_t)(bn * 64 + r) * 3136 + kb + kq * 4];
      Bs[(kq * 4 + 0) * 68 + r] = bv.x;
      Bs[(kq * 4 + 1) * 68 + r] = bv.y;
      Bs[(kq * 4 + 2) * 68 + r] = bv.z;
      Bs[(kq * 4 + 3) * 68 + r] = bv.w;
    }
    __syncthreads();
    #pragma unroll
    for (int k = 0; k < 32; ++k) {
      const float4 a4 = *(const float4*)&As[k * 68 + tm * 4];
      const float4 b4 = *(const float4*)&Bs[k * 68 + tn * 4];
      acc[0][0] += a4.x*b4.x; acc[0][1] += a4.x*b4.y; acc[0][2] += a4.x*b4.z; acc[0][3] += a4.x*b4.w;
      acc[1][0] += a4.y*b4.x; acc[1][1] += a4.y*b4.y; acc[1][2] += a4.y*b4.z; acc[1][3] += a4.y*b4.w;
      acc[2][0] += a4.z*b4.x; acc[2][1] += a4.z*b4.y; acc[2][2] += a4.z*b4.z; acc[2][3] += a4.z*b4.w;
      acc[3][0] += a4.w*b4.x; acc[3][1] += a4.w*b4.y; acc[3][2] += a4.w*b4.z; acc[3][3] += a4.w*b4.w;
    }
    __syncthreads();
  }
  float* Cz = ws + (bz ? WS_QPART : WS_VIS);
  #pragma unroll
  for (int i = 0; i < 4; ++i) {
    const int row = bm * 64 + tm * 4 + i;
    const int col0 = bn * 64 + tn * 4;
    float4 v;
    v.x = acc[i][0]; v.y = acc[i][1]; v.z = acc[i][2]; v.w = acc[i][3];
    *(float4*)&Cz[(size_t)row * 512 + col0] = v;
  }
}

// fc combine: VIS = (z0 partial in VIS) + (z1 partial in QPART) + fc_b
__global__ __launch_bounds__(256) void k_fccomb(
    const float* __restrict__ fc_b, float* __restrict__ ws)
{
  const int id = blockIdx.x * 256 + threadIdx.x;
  ws[WS_VIS + id] += ws[WS_QPART + id] + fc_b[id & 511];
}

// ---------------------------------------------------------------------------
// qgemm: 128x64 tile GEMM (h @ hfc_w^T), K=1024 split 8 -> QPART partials.
__global__ __launch_bounds__(256) void k_gemm2(
    const float* __restrict__ A, int lda,
    const float* __restrict__ B, int ldb,
    float* __restrict__ C, int ldc,
    int Kz, long strideCz)
{
  __shared__ float As[32 * 133];
  __shared__ float Bs[32 * 69];
  const int tid = threadIdx.x;
  const int bm = blockIdx.x, bn = blockIdx.y, bz = blockIdx.z;
  const int tm = tid >> 4, tn = tid & 15;
  float acc[8][4];
  #pragma unroll
  for (int i = 0; i < 8; ++i)
    #pragma unroll
    for (int j = 0; j < 4; ++j) acc[i][j] = 0.f;

  const int kbase0 = bz * Kz;
  for (int kk = 0; kk < Kz; kk += 32) {
    const int kb = kbase0 + kk;
    #pragma unroll
    for (int i = 0; i < 16; ++i) {
      const int e = tid + i * 256;
      const int k = e & 31, m = e >> 5;
      As[k * 133 + m] = A[(size_t)(bm * 128 + m) * lda + kb + k];
    }
    #pragma unroll
    for (int i = 0; i < 8; ++i) {
      const int e = tid + i * 256;
      const int k = e & 31, n = e >> 5;
      Bs[k * 69 + n] = B[(size_t)(bn * 64 + n) * ldb + kb + k];
    }
    __syncthreads();
    #pragma unroll
    for (int k = 0; k < 32; ++k) {
      const float4 a0 = *(const float4*)&As[k * 133 + tm * 8];
      const float4 a1 = *(const float4*)&As[k * 133 + tm * 8 + 4];
      const float4 b4 = *(const float4*)&Bs[k * 69 + tn * 4];
      const float av[8] = {a0.x, a0.y, a0.z, a0.w, a1.x, a1.y, a1.z, a1.w};
      const float bv[4] = {b4.x, b4.y, b4.z, b4.w};
      #pragma unroll
      for (int i = 0; i < 8; ++i)
        #pragma unroll
        for (int j = 0; j < 4; ++j)
          acc[i][j] += av[i] * bv[j];
    }
    __syncthreads();
  }
  float* Cz = C + (long)bz * strideCz;
  #pragma unroll
  for (int i = 0; i < 8; ++i) {
    const int row = bm * 128 + tm * 8 + i;
    const int col0 = bn * 64 + tn * 4;
    float4 v;
    v.x = acc[i][0]; v.y = acc[i][1]; v.z = acc[i][2]; v.w = acc[i][3];
    *(float4*)&Cz[(size_t)row * ldc + col0] = v;
  }
}

// ---------------------------------------------------------------------------
// Flash attention over one 64-row L-segment. grid (8 seg, 128 b), 512 thr.
__global__ __launch_bounds__(512) void k_attn(
    const float* __restrict__ enc, const float* __restrict__ hfc_b,
    float* __restrict__ ws)
{
  __shared__ float q_lds[1024];
  __shared__ float raw_lds[64];
  __shared__ float accw[8][1024];
  __shared__ float m_lds[8];
  __shared__ float z_lds[8];
  const int seg = blockIdx.x, b = blockIdx.y, tid = threadIdx.x;
  const float* qpart = ws + WS_QPART;
  for (int d = tid; d < 1024; d += 512) {
    float s = hfc_b[d];
    #pragma unroll
    for (int sp = 0; sp < 8; ++sp) s += qpart[sp * 131072 + b * 1024 + d];
    q_lds[d] = s;
  }
  __syncthreads();
  const int lane = tid & 63, wv = tid >> 6;
  const float4 q0 = *(const float4*)&q_lds[lane * 4];
  const float4 q1 = *(const float4*)&q_lds[lane * 4 + 256];
  const float4 q2 = *(const float4*)&q_lds[lane * 4 + 512];
  const float4 q3 = *(const float4*)&q_lds[lane * 4 + 768];
  const float* row = enc + (size_t)b * (NL * DH) + (size_t)seg * 64 * DH + lane * 4;
  float m = -INFINITY, z = 0.f;
  float4 ac0 = {0,0,0,0}, ac1 = {0,0,0,0}, ac2 = {0,0,0,0}, ac3 = {0,0,0,0};
  float4 e0 = *(const float4*)&row[wv * 1024];
  float4 e1 = *(const float4*)&row[wv * 1024 + 256];
  float4 e2 = *(const float4*)&row[wv * 1024 + 512];
  float4 e3 = *(const float4*)&row[wv * 1024 + 768];
  for (int r = 0; r < 8; ++r) {
    const int l = wv + (r << 3);
    const float4 c0_ = e0, c1_ = e1, c2_ = e2, c3_ = e3;
    if (r < 7) {
      const int ln = (l + 8) * 1024;
      e0 = *(const float4*)&row[ln];
      e1 = *(const float4*)&row[ln + 256];
      e2 = *(const float4*)&row[ln + 512];
      e3 = *(const float4*)&row[ln + 768];
    }
    float d = c0_.x*q0.x + c0_.y*q0.y + c0_.z*q0.z + c0_.w*q0.w;
    d += c1_.x*q1.x + c1_.y*q1.y + c1_.z*q1.z + c1_.w*q1.w;
    d += c2_.x*q2.x + c2_.y*q2.y + c2_.z*q2.z + c2_.w*q2.w;
    d += c3_.x*q3.x + c3_.y*q3.y + c3_.z*q3.z + c3_.w*q3.w;
    #pragma unroll
    for (int off = 32; off > 0; off >>= 1) d += __shfl_xor(d, off, 64);
    if (lane == 0) raw_lds[l] = d;
    const float mn = fmaxf(m, d);
    const float sc = expf(m - mn);
    const float p  = expf(d - mn);
    z = z * sc + p;
    ac0.x = ac0.x*sc + p*c0_.x; ac0.y = ac0.y*sc + p*c0_.y; ac0.z = ac0.z*sc + p*c0_.z; ac0.w = ac0.w*sc + p*c0_.w;
    ac1.x = ac1.x*sc + p*c1_.x; ac1.y = ac1.y*sc + p*c1_.y; ac1.z = ac1.z*sc + p*c1_.z; ac1.w = ac1.w*sc + p*c1_.w;
    ac2.x = ac2.x*sc + p*c2_.x; ac2.y = ac2.y*sc + p*c2_.y; ac2.z = ac2.z*sc + p*c2_.z; ac2.w = ac2.w*sc + p*c2_.w;
    ac3.x = ac3.x*sc + p*c3_.x; ac3.y = ac3.y*sc + p*c3_.y; ac3.z = ac3.z*sc + p*c3_.z; ac3.w = ac3.w*sc + p*c3_.w;
    m = mn;
  }
  *(float4*)&accw[wv][lane * 4      ] = ac0;
  *(float4*)&accw[wv][lane * 4 + 256] = ac1;
  *(float4*)&accw[wv][lane * 4 + 512] = ac2;
  *(float4*)&accw[wv][lane * 4 + 768] = ac3;
  if (lane == 0) { m_lds[wv] = m; z_lds[wv] = z; }
  __syncthreads();
  float M = m_lds[0];
  #pragma unroll
  for (int s = 1; s < 8; ++s) M = fmaxf(M, m_lds[s]);
  float ef[8];
  #pragma unroll
  for (int s = 0; s < 8; ++s) ef[s] = expf(m_lds[s] - M);
  float Z = 0.f;
  #pragma unroll
  for (int s = 0; s < 8; ++s) Z += ef[s] * z_lds[s];
  float* att = ws + WS_ATT + ((size_t)b * NSEG + seg) * 1032;
  for (int d = tid; d < 1024; d += 512) {
    float s = 0.f;
    #pragma unroll
    for (int w8 = 0; w8 < 8; ++w8) s += ef[w8] * accw[w8][d];
    att[d] = s;
  }
  if (tid == 0) { att[1024] = M; att[1025] = Z; }
  if (tid < 64) ws[WS_ATTRAW + b * 512 + seg * 64 + tid] = raw_lds[tid];
}

// ---------------------------------------------------------------------------
// Combine 8-seg partials ONCE per (b): weighted -> XCAT[512..1536),
// vis -> XCAT[0..512), scores -> out. 128 blocks x 256 thr.
__global__ __launch_bounds__(256) void k_comb(
    float* __restrict__ ws, float* __restrict__ out, int t)
{
  const int b = blockIdx.x, tid = threadIdx.x;
  const float* att = ws + WS_ATT + (size_t)b * NSEG * 1032;
  float* xcat = ws + WS_XCAT + (size_t)b * DCAT;
  float ms[NSEG], zs[NSEG];
  #pragma unroll
  for (int s = 0; s < NSEG; ++s) { ms[s] = att[s * 1032 + 1024]; zs[s] = att[s * 1032 + 1025]; }
  float M = ms[0];
  #pragma unroll
  for (int s = 1; s < NSEG; ++s) M = fmaxf(M, ms[s]);
  float ef[NSEG], Z = 0.f;
  #pragma unroll
  for (int s = 0; s < NSEG; ++s) { ef[s] = expf(ms[s] - M); Z += ef[s] * zs[s]; }
  const float inv = 1.f / Z;
  for (int i = tid; i < 512; i += 256)
    xcat[i] = ws[WS_VIS + ((size_t)b * NT + t) * DF + i];
  for (int d = tid; d < 1024; d += 256) {
    float w = 0.f;
    #pragma unroll
    for (int s = 0; s < NSEG; ++s) w += ef[s] * att[s * 1032 + d];
    xcat[512 + d] = w * inv;
  }
  for (int l = tid; l < 512; l += 256)
    out[SC_OFF + ((size_t)b * NT + t) * NL + l] =
        expf(ws[WS_ATTRAW + b * 512 + l] - M) * inv;
}

// ---------------------------------------------------------------------------
// Gates: gpart[bz] = xcat[:, bz*224:(bz+1)*224] @ W^T slice.
// grid (64 bn, 12 bz). 128x64 tile, 8x4/thread, BK=32.
__global__ __launch_bounds__(256) void k_gates(
    const float* __restrict__ w_ih, const float* __restrict__ w_hh,
    float* __restrict__ ws)
{
  __shared__ float As[32 * 132];
  __shared__ float Bs[32 * 68];
  const int tid = threadIdx.x;
  const int bn = blockIdx.x, bz = blockIdx.y;
  const int tm = tid >> 4, tn = tid & 15;
  float acc[8][4];
  #pragma unroll
  for (int i = 0; i < 8; ++i)
    #pragma unroll
    for (int j = 0; j < 4; ++j) acc[i][j] = 0.f;

  const float* xc = ws + WS_XCAT;
  for (int kk = 0; kk < 224; kk += 32) {
    const int kb = bz * 224 + kk;
    #pragma unroll
    for (int i = 0; i < 4; ++i) {
      const int e = tid + i * 256;
      const int r = e >> 3, kq = e & 7;
      const float4 av = *(const float4*)&xc[(size_t)r * DCAT + kb + kq * 4];
      As[(kq * 4 + 0) * 132 + r] = av.x;
      As[(kq * 4 + 1) * 132 + r] = av.y;
      As[(kq * 4 + 2) * 132 + r] = av.z;
      As[(kq * 4 + 3) * 132 + r] = av.w;
    }
    #pragma unroll
    for (int i = 0; i < 2; ++i) {
      const int e = tid + i * 256;
      const int n = e >> 3, kq = e & 7;
      const int g = bn * 64 + n;
      const float4 bv = (kb < DIN)
          ? *(const float4*)&w_ih[(size_t)g * DIN + kb + kq * 4]
          : *(const float4*)&w_hh[(size_t)g * DH + (kb - DIN) + kq * 4];
      Bs[(kq * 4 + 0) * 68 + n] = bv.x;
      Bs[(kq * 4 + 1) * 68 + n] = bv.y;
      Bs[(kq * 4 + 2) * 68 + n] = bv.z;
      Bs[(kq * 4 + 3) * 68 + n] = bv.w;
    }
    __syncthreads();
    #pragma unroll
    for (int k = 0; k < 32; ++k) {
      const float4 a0 = *(const float4*)&As[k * 132 + tm * 8];
      const float4 a1 = *(const float4*)&As[k * 132 + tm * 8 + 4];
      const float4 b4 = *(const float4*)&Bs[k * 68 + tn * 4];
      const float av[8] = {a0.x, a0.y, a0.z, a0.w, a1.x, a1.y, a1.z, a1.w};
      const float bv[4] = {b4.x, b4.y, b4.z, b4.w};
      #pragma unroll
      for (int i = 0; i < 8; ++i)
        #pragma unroll
        for (int j = 0; j < 4; ++j)
          acc[i][j] += av[i] * bv[j];
    }
    __syncthreads();
  }
  float* Cz = ws + WS_GPART + (size_t)bz * 524288;
  #pragma unroll
  for (int i = 0; i < 8; ++i) {
    const int b = tm * 8 + i;
    const int col0 = bn * 64 + tn * 4;
    float4 v;
    v.x = acc[i][0]; v.y = acc[i][1]; v.z = acc[i][2]; v.w = acc[i][3];
    *(float4*)&Cz[(size_t)b * 4096 + col0] = v;
  }
}

// ---------------------------------------------------------------------------
// Fused LSTM pointwise + actor + argmax + embed feedback. 128 blocks x 512 thr.
__global__ __launch_bounds__(512) void k_lstmactor(
    const float* __restrict__ emb_w, const float* __restrict__ actor_b,
    float* __restrict__ ws, float* __restrict__ out, int t, int last)
{
  __shared__ float xl[DCAT];
  __shared__ float ph[512];
  __shared__ float ae[128];
  __shared__ float bv[512];
  __shared__ int   bi[512];
  const int b = blockIdx.x, tid = threadIdx.x;
  float* xcat = ws + WS_XCAT + (size_t)b * DCAT;

  for (int i = tid; i < 416; i += 512)
    ((float4*)xl)[i] = ((const float4*)xcat)[i];

  const float* gpart = ws + WS_GPART;
  const float* bsum = ws + WS_BSUM;
  for (int j = tid; j < 1024; j += 512) {
    float g[4];
    #pragma unroll
    for (int gi = 0; gi < 4; ++gi) {
      const int x = gi * 1024 + j;
      float s = bsum[x];
      #pragma unroll
      for (int sp = 0; sp < NGZ; ++sp) s += gpart[(size_t)sp * 524288 + b * 4096 + x];
      g[gi] = s;
    }
    const float ii = 1.f / (1.f + expf(-g[0]));
    const float ff = 1.f / (1.f + expf(-g[1]));
    const float gg = tanhf(g[2]);
    const float oo = 1.f / (1.f + expf(-g[3]));
    const float c = ff * ws[WS_CBUF + b * 1024 + j] + ii * gg;
    const float h = oo * tanhf(c);
    ws[WS_CBUF + b * 1024 + j] = c;
    xl[1664 + j] = h;
    xcat[1664 + j] = h;
    if (last) { out[H_OFF + b * 1024 + j] = h; out[C_OFF + b * 1024 + j] = c; }
  }
  __syncthreads();

  {
    const int o = tid & 127;
    const int k0 = (tid >> 7) * 672;
    const float* APT = ws + WS_APT;
    float s = 0.f;
    #pragma unroll 8
    for (int k = k0; k < k0 + 672; ++k) s += xl[k] * APT[k * 128 + o];
    ph[tid] = s;
  }
  __syncthreads();
  if (tid < 128)
    ae[tid] = ph[tid] + ph[tid + 128] + ph[tid + 256] + ph[tid + 384] + actor_b[tid];
  __syncthreads();

  const float* EWT = ws + WS_EWT;
  float s = 0.f;
  #pragma unroll 8
  for (int j = 0; j < 128; ++j) s += ae[j] * EWT[j * 512 + tid];
  out[ACT_OFF + ((size_t)b * NT + t) * NV + tid] = s;
  bv[tid] = s; bi[tid] = tid;
  __syncthreads();
  for (int s2 = 256; s2 > 0; s2 >>= 1) {
    if (tid < s2) {
      float ov = bv[tid + s2]; int oi = bi[tid + s2];
      if (ov > bv[tid] || (ov == bv[tid] && oi < bi[tid])) { bv[tid] = ov; bi[tid] = oi; }
    }
    __syncthreads();
  }
  const int am = bi[0];
  if (tid < 128) xcat[1536 + tid] = emb_w[am * 128 + tid];
}

// ---------------------------------------------------------------------------
extern "C" void kernel_launch(void* const* d_in, const int* in_sizes, int n_in,
                              void* d_out, int out_size, void* d_ws, size_t ws_size,
                              hipStream_t stream)
{
  const float* enc     = (const float*)d_in[0];
  const float* frames  = (const float*)d_in[1];
  const float* h0      = (const float*)d_in[2];
  const float* c0      = (const float*)d_in[3];
  const float* emb_w   = (const float*)d_in[5];
  const float* go      = (const float*)d_in[6];
  const float* conv1_w = (const float*)d_in[7];
  const float* conv1_b = (const float*)d_in[8];
  const float* bn1_g   = (const float*)d_in[9];
  const float* bn1_b   = (const float*)d_in[10];
  const float* bn1_m   = (const float*)d_in[11];
  const float* bn1_v   = (const float*)d_in[12];
  const float* conv2_w = (const float*)d_in[13];
  const float* conv2_b = (const float*)d_in[14];
  const float* bn2_g   = (const float*)d_in[15];
  const float* bn2_b   = (const float*)d_in[16];
  const float* bn2_m   = (const float*)d_in[17];
  const float* bn2_v   = (const float*)d_in[18];
  const float* fc_w    = (const float*)d_in[19];
  const float* fc_b    = (const float*)d_in[20];
  const float* hfc_w   = (const float*)d_in[21];
  const float* hfc_b   = (const float*)d_in[22];
  const float* w_ih    = (const float*)d_in[23];
  const float* b_ih    = (const float*)d_in[24];
  const float* w_hh    = (const float*)d_in[25];
  const float* b_hh    = (const float*)d_in[26];
  const float* actor_w = (const float*)d_in[27];
  const float* actor_b = (const float*)d_in[28];
  float* out = (float*)d_out;
  float* ws  = (float*)d_ws;

  k_prep<<<2194, 256, 0, stream>>>(conv1_w, conv1_b, bn1_g, bn1_b, bn1_m, bn1_v,
      conv2_w, conv2_b, bn2_g, bn2_b, bn2_m, bn2_v, actor_w, emb_w, b_ih, b_hh, ws);
  k_init<<<128, 256, 0, stream>>>(h0, c0, go, ws);
  k_visconv<<<3200, 256, 0, stream>>>(frames, ws);
  k_gemmfc<<<dim3(400, 2), 256, 0, stream>>>(ws + WS_Y2F, fc_w, ws);
  k_fccomb<<<6400, 256, 0, stream>>>(fc_b, ws);

  for (int t = 0; t < NT; ++t) {
    k_gemm2<<<dim3(1, 16, 8), 256, 0, stream>>>(ws + WS_XCAT + 1664, DCAT,
        hfc_w, 1024, ws + WS_QPART, 1024, 128, 131072);
    k_attn<<<dim3(NSEG, 128), 512, 0, stream>>>(enc, hfc_b, ws);
    k_comb<<<128, 256, 0, stream>>>(ws, out, t);
    k_gates<<<dim3(64, NGZ), 256, 0, stream>>>(w_ih, w_hh, ws);
    k_lstmactor<<<128, 512, 0, stream>>>(emb_w, actor_b, ws, out, t,
                                         t == NT - 1 ? 1 : 0);
  }
}

// Round 15
// 5276.137 us; speedup vs baseline: 1.1956x; 1.1956x over previous
//
#include <hip/hip_runtime.h>
#include <cmath>

// ---------------------------------------------------------------------------
// ConvFrameDecoder — fp32, round 15.
// r14 post-mortem: visconv W-from-global destroyed the 16x on-CU reuse that
// LDS staging provided (26GB L2 traffic, latency-bound, 793->1828us).
// r15: visconv reverted to r13 verbatim (LDS-staged Wc); fc keeps r14's
// float4 staging (4-way conflicts, ~neutral). Everything else = r13.
// ---------------------------------------------------------------------------

#define NB   128
#define NT   25
#define NL   512
#define DH   1024
#define DF   512
#define DIN  1664
#define DCAT 2688
#define NV   512
#define NSEG 8
#define NGZ  12

// d_out offsets (floats): actions[128,25,512], scores[128,25,512,1], h, c
#define ACT_OFF 0
#define SC_OFF  1638400
#define H_OFF   3276800
#define C_OFF   3407872

// workspace offsets (floats); peak < 16,450,176 floats = 65.8 MB
#define WS_W1T   0u
#define WS_W2T   131072u
#define WS_APT   147456u
#define WS_EWT   491520u
#define WS_BSUM  557056u
#define WS_A1    561152u
#define WS_B1    561408u
#define WS_A2    561664u
#define WS_B2    561728u
#define WS_XCAT  561792u     // [128][2688] = [vis|weighted|e|h]
#define WS_CBUF  905856u     // [128][1024]
#define WS_QPART 1036928u    // [8][128][1024]; fc z=1 partial in setup
#define WS_VIS   4776576u    // [3200][512]
#define WS_Y2F   6414976u    // [3200][3136] — DEAD after fc; aliases below:
#define WS_ATT   6414976u    // [128][8][1032] (acc1024,m,z)
#define WS_ATTRAW 7471744u   // [128][512]
#define WS_GPART 7537280u    // [12][128][4096] -> ends 13828736

// ---------------------------------------------------------------------------
__global__ __launch_bounds__(256) void k_prep(
    const float* __restrict__ conv1_w, const float* __restrict__ conv1_b,
    const float* __restrict__ bn1_g, const float* __restrict__ bn1_b,
    const float* __restrict__ bn1_m, const float* __restrict__ bn1_v,
    const float* __restrict__ conv2_w, const float* __restrict__ conv2_b,
    const float* __restrict__ bn2_g, const float* __restrict__ bn2_b,
    const float* __restrict__ bn2_m, const float* __restrict__ bn2_v,
    const float* __restrict__ actor_w, const float* __restrict__ emb_w,
    const float* __restrict__ b_ih, const float* __restrict__ b_hh,
    float* __restrict__ ws)
{
  int i = blockIdx.x * 256 + threadIdx.x;
  if (i < 131072) {                      // W1T[c][o] = conv1_w[o][c]
    int c = i >> 8, o = i & 255;
    ws[WS_W1T + i] = conv1_w[o * 512 + c];
    return;
  }
  i -= 131072;
  if (i < 16384) {                       // W2T[c][o] = conv2_w[o][c]
    int c = i >> 6, o = i & 63;
    ws[WS_W2T + i] = conv2_w[o * 256 + c];
    return;
  }
  i -= 16384;
  if (i < 344064) {                      // APT[k][o], cont=[h|inp] -> xcat=[inp|h]
    int k = i >> 7, o = i & 127;
    int src = (k < DIN) ? (DH + k) : (k - DIN);
    ws[WS_APT + i] = actor_w[o * DCAT + src];
    return;
  }
  i -= 344064;
  if (i < 65536) {                       // EWT[j][v] = emb_w[v][j]
    int j = i >> 9, v = i & 511;
    ws[WS_EWT + i] = emb_w[v * 128 + j];
    return;
  }
  i -= 65536;
  if (i < 4096) { ws[WS_BSUM + i] = b_ih[i] + b_hh[i]; return; }
  i -= 4096;
  if (i < 256) {
    float a = bn1_g[i] / sqrtf(bn1_v[i] + 1e-5f);
    ws[WS_A1 + i] = a;
    ws[WS_B1 + i] = a * (conv1_b[i] - bn1_m[i]) + bn1_b[i];
    return;
  }
  i -= 256;
  if (i < 64) {
    float a = bn2_g[i] / sqrtf(bn2_v[i] + 1e-5f);
    ws[WS_A2 + i] = a;
    ws[WS_B2 + i] = a * (conv2_b[i] - bn2_m[i]) + bn2_b[i];
  }
}

// ---------------------------------------------------------------------------
__global__ __launch_bounds__(256) void k_init(
    const float* __restrict__ h0, const float* __restrict__ c0,
    const float* __restrict__ go, float* __restrict__ ws)
{
  int b = blockIdx.x, tid = threadIdx.x;
  if (tid < 128) ws[WS_XCAT + b * DCAT + 1536 + tid] = go[tid];
  for (int d = tid; d < 1024; d += 256) {
    ws[WS_XCAT + b * DCAT + 1664 + d] = h0[b * 1024 + d];
    ws[WS_CBUF + b * 1024 + d] = c0[b * 1024 + d];
  }
}

// ---------------------------------------------------------------------------
// visconv (r13 verbatim: LDS-staged Wc for 16x on-CU reuse)
__global__ __launch_bounds__(256) void k_visconv(
    const float* __restrict__ frames, float* __restrict__ ws)
{
  __shared__ float lds[10240];           // 40KB
  float* Xc  = lds;
  float* Wc  = lds + 2048;
  float* Y1c = lds;
  const int bt = blockIdx.x, tid = threadIdx.x;
  const int tn = tid & 15, tm = tid >> 4;
  const float* img = frames + (size_t)bt * 25088;
  const float* W1T = ws + WS_W1T;
  const float* W2T = ws + WS_W2T;

  float acc1[4][16];
  #pragma unroll
  for (int m = 0; m < 4; ++m)
    #pragma unroll
    for (int j = 0; j < 16; ++j) acc1[m][j] = 0.f;

  for (int i = tid; i < 2048; i += 256) Xc[i] = 0.f;
  __syncthreads();

  for (int ch = 0; ch < 16; ++ch) {
    for (int i4 = tid; i4 < 392; i4 += 256) {
      float4 v = *(const float4*)(img + ch * 1568 + (i4 << 2));
      int gi = i4 << 2;
      #pragma unroll
      for (int j = 0; j < 4; ++j) {
        int e = gi + j, c = e / 49, hw = e - c * 49;
        Xc[(c << 6) + hw] = (&v.x)[j];
      }
    }
    const float4* wsrc = (const float4*)(W1T + (ch << 13));
    for (int i = tid; i < 2048; i += 256) ((float4*)Wc)[i] = wsrc[i];
    __syncthreads();
    #pragma unroll 4
    for (int c = 0; c < 32; ++c) {
      const float4 a4 = *(const float4*)&Xc[(c << 6) + (tm << 2)];
      float a[4] = {a4.x, a4.y, a4.z, a4.w};
      const float* wr = &Wc[(c << 8) + (tn << 2)];
      #pragma unroll
      for (int ko = 0; ko < 4; ++ko) {
        const float4 b4 = *(const float4*)&wr[ko << 6];
        float bb[4] = {b4.x, b4.y, b4.z, b4.w};
        #pragma unroll
        for (int m = 0; m < 4; ++m)
          #pragma unroll
          for (int jo = 0; jo < 4; ++jo)
            acc1[m][(ko << 2) + jo] += a[m] * bb[jo];
      }
    }
    __syncthreads();
  }

  #pragma unroll
  for (int ko = 0; ko < 4; ++ko)
    #pragma unroll
    for (int jo = 0; jo < 4; ++jo) {
      const int o = (ko << 6) + (tn << 2) + jo;
      const float aa = ws[WS_A1 + o], bb = ws[WS_B1 + o];
      #pragma unroll
      for (int m = 0; m < 4; ++m)
        acc1[m][(ko << 2) + jo] = fmaxf(aa * acc1[m][(ko << 2) + jo] + bb, 0.f);
    }

  float acc2[4][4];
  #pragma unroll
  for (int m = 0; m < 4; ++m)
    #pragma unroll
    for (int j = 0; j < 4; ++j) acc2[m][j] = 0.f;
  for (int r = 0; r < 2; ++r) {
    __syncthreads();
    #pragma unroll
    for (int kh = 0; kh < 2; ++kh) {
      const int ko = (r << 1) + kh;
      #pragma unroll
      for (int jo = 0; jo < 4; ++jo) {
        const int row = (kh << 6) + (tn << 2) + jo;
        float4 v;
        v.x = acc1[0][(ko << 2) + jo]; v.y = acc1[1][(ko << 2) + jo];
        v.z = acc1[2][(ko << 2) + jo]; v.w = acc1[3][(ko << 2) + jo];
        *(float4*)&Y1c[row * 68 + (tm << 2)] = v;
      }
    }
    __syncthreads();
    #pragma unroll 4
    for (int c2l = 0; c2l < 128; ++c2l) {
      const float4 a4 = *(const float4*)&Y1c[c2l * 68 + (tm << 2)];
      float a[4] = {a4.x, a4.y, a4.z, a4.w};
      const float4 b4 = *(const float4*)&W2T[(((r << 7) + c2l) << 6) + (tn << 2)];
      float bb[4] = {b4.x, b4.y, b4.z, b4.w};
      #pragma unroll
      for (int m = 0; m < 4; ++m)
        #pragma unroll
        for (int jo = 0; jo < 4; ++jo)
          acc2[m][jo] += a[m] * bb[jo];
    }
  }

  float* y2f = ws + WS_Y2F + (size_t)bt * 3136;
  #pragma unroll
  for (int jo = 0; jo < 4; ++jo) {
    const int o2 = (tn << 2) + jo;
    const float aa = ws[WS_A2 + o2], bb = ws[WS_B2 + o2];
    #pragma unroll
    for (int m = 0; m < 4; ++m) {
      const int hw = (tm << 2) + m;
      if (hw < 49) y2f[o2 * 49 + hw] = fmaxf(aa * acc2[m][jo] + bb, 0.f);
    }
  }
}

// ---------------------------------------------------------------------------
// fc GEMM, 64x64 tiles, XCD-swizzled, float4 staging. grid (400, 2).
__global__ __launch_bounds__(256) void k_gemmfc(
    const float* __restrict__ A, const float* __restrict__ B,
    float* __restrict__ ws)
{
  __shared__ float As[32 * 68];
  __shared__ float Bs[32 * 68];
  const int tid = threadIdx.x;
  const int fid = blockIdx.x, bz = blockIdx.y;
  const int w = (fid & 7) * 50 + (fid >> 3);
  const int bm = w >> 3, bn = w & 7;
  const int tm = tid >> 4, tn = tid & 15;
  float acc[4][4];
  #pragma unroll
  for (int i = 0; i < 4; ++i)
    #pragma unroll
    for (int j = 0; j < 4; ++j) acc[i][j] = 0.f;

  const int kbase0 = bz * 1568;
  for (int kk = 0; kk < 1568; kk += 32) {
    const int kb = kbase0 + kk;
    #pragma unroll
    for (int i = 0; i < 2; ++i) {        // e in [0,512): r=e>>3, kq=e&7
      const int e = tid + i * 256;
      const int r = e >> 3, kq = e & 7;
      const float4 av = *(const float4*)&A[(size_t)(bm * 64 + r) * 3136 + kb + kq * 4];
      As[(kq * 4 + 0) * 68 + r] = av.x;
      As[(kq * 4 + 1) * 68 + r] = av.y;
      As[(kq * 4 + 2) * 68 + r] = av.z;
      As[(kq * 4 + 3) * 68 + r] = av.w;
      const float4 bv = *(const float4*)&B[(size_t)(bn * 64 + r) * 3136 + kb + kq * 4];
      Bs[(kq * 4 + 0) * 68 + r] = bv.x;
      Bs[(kq * 4 + 1) * 68 + r] = bv.y;
      Bs[(kq * 4 + 2) * 68 + r] = bv.z;
      Bs[(kq * 4 + 3) * 68 + r] = bv.w;
    }
    __syncthreads();
    #pragma unroll
    for (int k = 0; k < 32; ++k) {
      const float4 a4 = *(const float4*)&As[k * 68 + tm * 4];
      const float4 b4 = *(const float4*)&Bs[k * 68 + tn * 4];
      acc[0][0] += a4.x*b4.x; acc[0][1] += a4.x*b4.y; acc[0][2] += a4.x*b4.z; acc[0][3] += a4.x*b4.w;
      acc[1][0] += a4.y*b4.x; acc[1][1] += a4.y*b4.y; acc[1][2] += a4.y*b4.z; acc[1][3] += a4.y*b4.w;
      acc[2][0] += a4.z*b4.x; acc[2][1] += a4.z*b4.y; acc[2][2] += a4.z*b4.z; acc[2][3] += a4.z*b4.w;
      acc[3][0] += a4.w*b4.x; acc[3][1] += a4.w*b4.y; acc[3][2] += a4.w*b4.z; acc[3][3] += a4.w*b4.w;
    }
    __syncthreads();
  }
  float* Cz = ws + (bz ? WS_QPART : WS_VIS);
  #pragma unroll
  for (int i = 0; i < 4; ++i) {
    const int row = bm * 64 + tm * 4 + i;
    const int col0 = bn * 64 + tn * 4;
    float4 v;
    v.x = acc[i][0]; v.y = acc[i][1]; v.z = acc[i][2]; v.w = acc[i][3];
    *(float4*)&Cz[(size_t)row * 512 + col0] = v;
  }
}

// fc combine: VIS = (z0 partial in VIS) + (z1 partial in QPART) + fc_b
__global__ __launch_bounds__(256) void k_fccomb(
    const float* __restrict__ fc_b, float* __restrict__ ws)
{
  const int id = blockIdx.x * 256 + threadIdx.x;
  ws[WS_VIS + id] += ws[WS_QPART + id] + fc_b[id & 511];
}

// ---------------------------------------------------------------------------
// qgemm: 128x64 tile GEMM (h @ hfc_w^T), K=1024 split 8 -> QPART partials.
__global__ __launch_bounds__(256) void k_gemm2(
    const float* __restrict__ A, int lda,
    const float* __restrict__ B, int ldb,
    float* __restrict__ C, int ldc,
    int Kz, long strideCz)
{
  __shared__ float As[32 * 133];
  __shared__ float Bs[32 * 69];
  const int tid = threadIdx.x;
  const int bm = blockIdx.x, bn = blockIdx.y, bz = blockIdx.z;
  const int tm = tid >> 4, tn = tid & 15;
  float acc[8][4];
  #pragma unroll
  for (int i = 0; i < 8; ++i)
    #pragma unroll
    for (int j = 0; j < 4; ++j) acc[i][j] = 0.f;

  const int kbase0 = bz * Kz;
  for (int kk = 0; kk < Kz; kk += 32) {
    const int kb = kbase0 + kk;
    #pragma unroll
    for (int i = 0; i < 16; ++i) {
      const int e = tid + i * 256;
      const int k = e & 31, m = e >> 5;
      As[k * 133 + m] = A[(size_t)(bm * 128 + m) * lda + kb + k];
    }
    #pragma unroll
    for (int i = 0; i < 8; ++i) {
      const int e = tid + i * 256;
      const int k = e & 31, n = e >> 5;
      Bs[k * 69 + n] = B[(size_t)(bn * 64 + n) * ldb + kb + k];
    }
    __syncthreads();
    #pragma unroll
    for (int k = 0; k < 32; ++k) {
      const float4 a0 = *(const float4*)&As[k * 133 + tm * 8];
      const float4 a1 = *(const float4*)&As[k * 133 + tm * 8 + 4];
      const float4 b4 = *(const float4*)&Bs[k * 69 + tn * 4];
      const float av[8] = {a0.x, a0.y, a0.z, a0.w, a1.x, a1.y, a1.z, a1.w};
      const float bv[4] = {b4.x, b4.y, b4.z, b4.w};
      #pragma unroll
      for (int i = 0; i < 8; ++i)
        #pragma unroll
        for (int j = 0; j < 4; ++j)
          acc[i][j] += av[i] * bv[j];
    }
    __syncthreads();
  }
  float* Cz = C + (long)bz * strideCz;
  #pragma unroll
  for (int i = 0; i < 8; ++i) {
    const int row = bm * 128 + tm * 8 + i;
    const int col0 = bn * 64 + tn * 4;
    float4 v;
    v.x = acc[i][0]; v.y = acc[i][1]; v.z = acc[i][2]; v.w = acc[i][3];
    *(float4*)&Cz[(size_t)row * ldc + col0] = v;
  }
}

// ---------------------------------------------------------------------------
// Flash attention over one 64-row L-segment. grid (8 seg, 128 b), 512 thr.
__global__ __launch_bounds__(512) void k_attn(
    const float* __restrict__ enc, const float* __restrict__ hfc_b,
    float* __restrict__ ws)
{
  __shared__ float q_lds[1024];
  __shared__ float raw_lds[64];
  __shared__ float accw[8][1024];
  __shared__ float m_lds[8];
  __shared__ float z_lds[8];
  const int seg = blockIdx.x, b = blockIdx.y, tid = threadIdx.x;
  const float* qpart = ws + WS_QPART;
  for (int d = tid; d < 1024; d += 512) {
    float s = hfc_b[d];
    #pragma unroll
    for (int sp = 0; sp < 8; ++sp) s += qpart[sp * 131072 + b * 1024 + d];
    q_lds[d] = s;
  }
  __syncthreads();
  const int lane = tid & 63, wv = tid >> 6;
  const float4 q0 = *(const float4*)&q_lds[lane * 4];
  const float4 q1 = *(const float4*)&q_lds[lane * 4 + 256];
  const float4 q2 = *(const float4*)&q_lds[lane * 4 + 512];
  const float4 q3 = *(const float4*)&q_lds[lane * 4 + 768];
  const float* row = enc + (size_t)b * (NL * DH) + (size_t)seg * 64 * DH + lane * 4;
  float m = -INFINITY, z = 0.f;
  float4 ac0 = {0,0,0,0}, ac1 = {0,0,0,0}, ac2 = {0,0,0,0}, ac3 = {0,0,0,0};
  float4 e0 = *(const float4*)&row[wv * 1024];
  float4 e1 = *(const float4*)&row[wv * 1024 + 256];
  float4 e2 = *(const float4*)&row[wv * 1024 + 512];
  float4 e3 = *(const float4*)&row[wv * 1024 + 768];
  for (int r = 0; r < 8; ++r) {
    const int l = wv + (r << 3);
    const float4 c0_ = e0, c1_ = e1, c2_ = e2, c3_ = e3;
    if (r < 7) {
      const int ln = (l + 8) * 1024;
      e0 = *(const float4*)&row[ln];
      e1 = *(const float4*)&row[ln + 256];
      e2 = *(const float4*)&row[ln + 512];
      e3 = *(const float4*)&row[ln + 768];
    }
    float d = c0_.x*q0.x + c0_.y*q0.y + c0_.z*q0.z + c0_.w*q0.w;
    d += c1_.x*q1.x + c1_.y*q1.y + c1_.z*q1.z + c1_.w*q1.w;
    d += c2_.x*q2.x + c2_.y*q2.y + c2_.z*q2.z + c2_.w*q2.w;
    d += c3_.x*q3.x + c3_.y*q3.y + c3_.z*q3.z + c3_.w*q3.w;
    #pragma unroll
    for (int off = 32; off > 0; off >>= 1) d += __shfl_xor(d, off, 64);
    if (lane == 0) raw_lds[l] = d;
    const float mn = fmaxf(m, d);
    const float sc = expf(m - mn);
    const float p  = expf(d - mn);
    z = z * sc + p;
    ac0.x = ac0.x*sc + p*c0_.x; ac0.y = ac0.y*sc + p*c0_.y; ac0.z = ac0.z*sc + p*c0_.z; ac0.w = ac0.w*sc + p*c0_.w;
    ac1.x = ac1.x*sc + p*c1_.x; ac1.y = ac1.y*sc + p*c1_.y; ac1.z = ac1.z*sc + p*c1_.z; ac1.w = ac1.w*sc + p*c1_.w;
    ac2.x = ac2.x*sc + p*c2_.x; ac2.y = ac2.y*sc + p*c2_.y; ac2.z = ac2.z*sc + p*c2_.z; ac2.w = ac2.w*sc + p*c2_.w;
    ac3.x = ac3.x*sc + p*c3_.x; ac3.y = ac3.y*sc + p*c3_.y; ac3.z = ac3.z*sc + p*c3_.z; ac3.w = ac3.w*sc + p*c3_.w;
    m = mn;
  }
  *(float4*)&accw[wv][lane * 4      ] = ac0;
  *(float4*)&accw[wv][lane * 4 + 256] = ac1;
  *(float4*)&accw[wv][lane * 4 + 512] = ac2;
  *(float4*)&accw[wv][lane * 4 + 768] = ac3;
  if (lane == 0) { m_lds[wv] = m; z_lds[wv] = z; }
  __syncthreads();
  float M = m_lds[0];
  #pragma unroll
  for (int s = 1; s < 8; ++s) M = fmaxf(M, m_lds[s]);
  float ef[8];
  #pragma unroll
  for (int s = 0; s < 8; ++s) ef[s] = expf(m_lds[s] - M);
  float Z = 0.f;
  #pragma unroll
  for (int s = 0; s < 8; ++s) Z += ef[s] * z_lds[s];
  float* att = ws + WS_ATT + ((size_t)b * NSEG + seg) * 1032;
  for (int d = tid; d < 1024; d += 512) {
    float s = 0.f;
    #pragma unroll
    for (int w8 = 0; w8 < 8; ++w8) s += ef[w8] * accw[w8][d];
    att[d] = s;
  }
  if (tid == 0) { att[1024] = M; att[1025] = Z; }
  if (tid < 64) ws[WS_ATTRAW + b * 512 + seg * 64 + tid] = raw_lds[tid];
}

// ---------------------------------------------------------------------------
// Combine 8-seg partials ONCE per (b). 128 blocks x 256 thr.
__global__ __launch_bounds__(256) void k_comb(
    float* __restrict__ ws, float* __restrict__ out, int t)
{
  const int b = blockIdx.x, tid = threadIdx.x;
  const float* att = ws + WS_ATT + (size_t)b * NSEG * 1032;
  float* xcat = ws + WS_XCAT + (size_t)b * DCAT;
  float ms[NSEG], zs[NSEG];
  #pragma unroll
  for (int s = 0; s < NSEG; ++s) { ms[s] = att[s * 1032 + 1024]; zs[s] = att[s * 1032 + 1025]; }
  float M = ms[0];
  #pragma unroll
  for (int s = 1; s < NSEG; ++s) M = fmaxf(M, ms[s]);
  float ef[NSEG], Z = 0.f;
  #pragma unroll
  for (int s = 0; s < NSEG; ++s) { ef[s] = expf(ms[s] - M); Z += ef[s] * zs[s]; }
  const float inv = 1.f / Z;
  for (int i = tid; i < 512; i += 256)
    xcat[i] = ws[WS_VIS + ((size_t)b * NT + t) * DF + i];
  for (int d = tid; d < 1024; d += 256) {
    float w = 0.f;
    #pragma unroll
    for (int s = 0; s < NSEG; ++s) w += ef[s] * att[s * 1032 + d];
    xcat[512 + d] = w * inv;
  }
  for (int l = tid; l < 512; l += 256)
    out[SC_OFF + ((size_t)b * NT + t) * NL + l] =
        expf(ws[WS_ATTRAW + b * 512 + l] - M) * inv;
}

// ---------------------------------------------------------------------------
// Gates: gpart[bz] = xcat[:, bz*224:(bz+1)*224] @ W^T slice.
// grid (64 bn, 12 bz). 128x64 tile, 8x4/thread, BK=32.
__global__ __launch_bounds__(256) void k_gates(
    const float* __restrict__ w_ih, const float* __restrict__ w_hh,
    float* __restrict__ ws)
{
  __shared__ float As[32 * 132];
  __shared__ float Bs[32 * 68];
  const int tid = threadIdx.x;
  const int bn = blockIdx.x, bz = blockIdx.y;
  const int tm = tid >> 4, tn = tid & 15;
  float acc[8][4];
  #pragma unroll
  for (int i = 0; i < 8; ++i)
    #pragma unroll
    for (int j = 0; j < 4; ++j) acc[i][j] = 0.f;

  const float* xc = ws + WS_XCAT;
  for (int kk = 0; kk < 224; kk += 32) {
    const int kb = bz * 224 + kk;
    #pragma unroll
    for (int i = 0; i < 4; ++i) {
      const int e = tid + i * 256;
      const int r = e >> 3, kq = e & 7;
      const float4 av = *(const float4*)&xc[(size_t)r * DCAT + kb + kq * 4];
      As[(kq * 4 + 0) * 132 + r] = av.x;
      As[(kq * 4 + 1) * 132 + r] = av.y;
      As[(kq * 4 + 2) * 132 + r] = av.z;
      As[(kq * 4 + 3) * 132 + r] = av.w;
    }
    #pragma unroll
    for (int i = 0; i < 2; ++i) {
      const int e = tid + i * 256;
      const int n = e >> 3, kq = e & 7;
      const int g = bn * 64 + n;
      const float4 bv = (kb < DIN)
          ? *(const float4*)&w_ih[(size_t)g * DIN + kb + kq * 4]
          : *(const float4*)&w_hh[(size_t)g * DH + (kb - DIN) + kq * 4];
      Bs[(kq * 4 + 0) * 68 + n] = bv.x;
      Bs[(kq * 4 + 1) * 68 + n] = bv.y;
      Bs[(kq * 4 + 2) * 68 + n] = bv.z;
      Bs[(kq * 4 + 3) * 68 + n] = bv.w;
    }
    __syncthreads();
    #pragma unroll
    for (int k = 0; k < 32; ++k) {
      const float4 a0 = *(const float4*)&As[k * 132 + tm * 8];
      const float4 a1 = *(const float4*)&As[k * 132 + tm * 8 + 4];
      const float4 b4 = *(const float4*)&Bs[k * 68 + tn * 4];
      const float av[8] = {a0.x, a0.y, a0.z, a0.w, a1.x, a1.y, a1.z, a1.w};
      const float bv[4] = {b4.x, b4.y, b4.z, b4.w};
      #pragma unroll
      for (int i = 0; i < 8; ++i)
        #pragma unroll
        for (int j = 0; j < 4; ++j)
          acc[i][j] += av[i] * bv[j];
    }
    __syncthreads();
  }
  float* Cz = ws + WS_GPART + (size_t)bz * 524288;
  #pragma unroll
  for (int i = 0; i < 8; ++i) {
    const int b = tm * 8 + i;
    const int col0 = bn * 64 + tn * 4;
    float4 v;
    v.x = acc[i][0]; v.y = acc[i][1]; v.z = acc[i][2]; v.w = acc[i][3];
    *(float4*)&Cz[(size_t)b * 4096 + col0] = v;
  }
}

// ---------------------------------------------------------------------------
// Fused LSTM pointwise + actor + argmax + embed feedback. 128 blocks x 512 thr.
__global__ __launch_bounds__(512) void k_lstmactor(
    const float* __restrict__ emb_w, const float* __restrict__ actor_b,
    float* __restrict__ ws, float* __restrict__ out, int t, int last)
{
  __shared__ float xl[DCAT];
  __shared__ float ph[512];
  __shared__ float ae[128];
  __shared__ float bv[512];
  __shared__ int   bi[512];
  const int b = blockIdx.x, tid = threadIdx.x;
  float* xcat = ws + WS_XCAT + (size_t)b * DCAT;

  for (int i = tid; i < 416; i += 512)
    ((float4*)xl)[i] = ((const float4*)xcat)[i];

  const float* gpart = ws + WS_GPART;
  const float* bsum = ws + WS_BSUM;
  for (int j = tid; j < 1024; j += 512) {
    float g[4];
    #pragma unroll
    for (int gi = 0; gi < 4; ++gi) {
      const int x = gi * 1024 + j;
      float s = bsum[x];
      #pragma unroll
      for (int sp = 0; sp < NGZ; ++sp) s += gpart[(size_t)sp * 524288 + b * 4096 + x];
      g[gi] = s;
    }
    const float ii = 1.f / (1.f + expf(-g[0]));
    const float ff = 1.f / (1.f + expf(-g[1]));
    const float gg = tanhf(g[2]);
    const float oo = 1.f / (1.f + expf(-g[3]));
    const float c = ff * ws[WS_CBUF + b * 1024 + j] + ii * gg;
    const float h = oo * tanhf(c);
    ws[WS_CBUF + b * 1024 + j] = c;
    xl[1664 + j] = h;
    xcat[1664 + j] = h;
    if (last) { out[H_OFF + b * 1024 + j] = h; out[C_OFF + b * 1024 + j] = c; }
  }
  __syncthreads();

  {
    const int o = tid & 127;
    const int k0 = (tid >> 7) * 672;
    const float* APT = ws + WS_APT;
    float s = 0.f;
    #pragma unroll 8
    for (int k = k0; k < k0 + 672; ++k) s += xl[k] * APT[k * 128 + o];
    ph[tid] = s;
  }
  __syncthreads();
  if (tid < 128)
    ae[tid] = ph[tid] + ph[tid + 128] + ph[tid + 256] + ph[tid + 384] + actor_b[tid];
  __syncthreads();

  const float* EWT = ws + WS_EWT;
  float s = 0.f;
  #pragma unroll 8
  for (int j = 0; j < 128; ++j) s += ae[j] * EWT[j * 512 + tid];
  out[ACT_OFF + ((size_t)b * NT + t) * NV + tid] = s;
  bv[tid] = s; bi[tid] = tid;
  __syncthreads();
  for (int s2 = 256; s2 > 0; s2 >>= 1) {
    if (tid < s2) {
      float ov = bv[tid + s2]; int oi = bi[tid + s2];
      if (ov > bv[tid] || (ov == bv[tid] && oi < bi[tid])) { bv[tid] = ov; bi[tid] = oi; }
    }
    __syncthreads();
  }
  const int am = bi[0];
  if (tid < 128) xcat[1536 + tid] = emb_w[am * 128 + tid];
}

// ---------------------------------------------------------------------------
extern "C" void kernel_launch(void* const* d_in, const int* in_sizes, int n_in,
                              void* d_out, int out_size, void* d_ws, size_t ws_size,
                              hipStream_t stream)
{
  const float* enc     = (const float*)d_in[0];
  const float* frames  = (const float*)d_in[1];
  const float* h0      = (const float*)d_in[2];
  const float* c0      = (const float*)d_in[3];
  const float* emb_w   = (const float*)d_in[5];
  const float* go      = (const float*)d_in[6];
  const float* conv1_w = (const float*)d_in[7];
  const float* conv1_b = (const float*)d_in[8];
  const float* bn1_g   = (const float*)d_in[9];
  const float* bn1_b   = (const float*)d_in[10];
  const float* bn1_m   = (const float*)d_in[11];
  const float* bn1_v   = (const float*)d_in[12];
  const float* conv2_w = (const float*)d_in[13];
  const float* conv2_b = (const float*)d_in[14];
  const float* bn2_g   = (const float*)d_in[15];
  const float* bn2_b   = (const float*)d_in[16];
  const float* bn2_m   = (const float*)d_in[17];
  const float* bn2_v   = (const float*)d_in[18];
  const float* fc_w    = (const float*)d_in[19];
  const float* fc_b    = (const float*)d_in[20];
  const float* hfc_w   = (const float*)d_in[21];
  const float* hfc_b   = (const float*)d_in[22];
  const float* w_ih    = (const float*)d_in[23];
  const float* b_ih    = (const float*)d_in[24];
  const float* w_hh    = (const float*)d_in[25];
  const float* b_hh    = (const float*)d_in[26];
  const float* actor_w = (const float*)d_in[27];
  const float* actor_b = (const float*)d_in[28];
  float* out = (float*)d_out;
  float* ws  = (float*)d_ws;

  k_prep<<<2194, 256, 0, stream>>>(conv1_w, conv1_b, bn1_g, bn1_b, bn1_m, bn1_v,
      conv2_w, conv2_b, bn2_g, bn2_b, bn2_m, bn2_v, actor_w, emb_w, b_ih, b_hh, ws);
  k_init<<<128, 256, 0, stream>>>(h0, c0, go, ws);
  k_visconv<<<3200, 256, 0, stream>>>(frames, ws);
  k_gemmfc<<<dim3(400, 2), 256, 0, stream>>>(ws + WS_Y2F, fc_w, ws);
  k_fccomb<<<6400, 256, 0, stream>>>(fc_b, ws);

  for (int t = 0; t < NT; ++t) {
    k_gemm2<<<dim3(1, 16, 8), 256, 0, stream>>>(ws + WS_XCAT + 1664, DCAT,
        hfc_w, 1024, ws + WS_QPART, 1024, 128, 131072);
    k_attn<<<dim3(NSEG, 128), 512, 0, stream>>>(enc, hfc_b, ws);
    k_comb<<<128, 256, 0, stream>>>(ws, out, t);
    k_gates<<<dim3(64, NGZ), 256, 0, stream>>>(w_ih, w_hh, ws);
    k_lstmactor<<<128, 512, 0, stream>>>(emb_w, actor_b, ws, out, t,
                                         t == NT - 1 ? 1 : 0);
  }
}

// Round 16
// 5275.708 us; speedup vs baseline: 1.1957x; 1.0001x over previous
//
#include <hip/hip_runtime.h>
#include <cmath>

// ---------------------------------------------------------------------------
// ConvFrameDecoder — fp32, round 16.
// r15 baseline 5276us. Single delta: k_attn 3-set explicit register prefetch
// (rows preloaded A,B,C; fully unrolled 8-row loop; ~2 load-sets in flight
// per compute) to cover the ~900cyc HBM latency that capped attn at
// ~4.5 TB/s with depth-1 prefetch. No runtime-indexed register arrays.
// Everything else byte-identical to r15.
// ---------------------------------------------------------------------------

#define NB   128
#define NT   25
#define NL   512
#define DH   1024
#define DF   512
#define DIN  1664
#define DCAT 2688
#define NV   512
#define NSEG 8
#define NGZ  12

// d_out offsets (floats): actions[128,25,512], scores[128,25,512,1], h, c
#define ACT_OFF 0
#define SC_OFF  1638400
#define H_OFF   3276800
#define C_OFF   3407872

// workspace offsets (floats); peak < 16,450,176 floats = 65.8 MB
#define WS_W1T   0u
#define WS_W2T   131072u
#define WS_APT   147456u
#define WS_EWT   491520u
#define WS_BSUM  557056u
#define WS_A1    561152u
#define WS_B1    561408u
#define WS_A2    561664u
#define WS_B2    561728u
#define WS_XCAT  561792u     // [128][2688] = [vis|weighted|e|h]
#define WS_CBUF  905856u     // [128][1024]
#define WS_QPART 1036928u    // [8][128][1024]; fc z=1 partial in setup
#define WS_VIS   4776576u    // [3200][512]
#define WS_Y2F   6414976u    // [3200][3136] — DEAD after fc; aliases below:
#define WS_ATT   6414976u    // [128][8][1032] (acc1024,m,z)
#define WS_ATTRAW 7471744u   // [128][512]
#define WS_GPART 7537280u    // [12][128][4096] -> ends 13828736

// ---------------------------------------------------------------------------
__global__ __launch_bounds__(256) void k_prep(
    const float* __restrict__ conv1_w, const float* __restrict__ conv1_b,
    const float* __restrict__ bn1_g, const float* __restrict__ bn1_b,
    const float* __restrict__ bn1_m, const float* __restrict__ bn1_v,
    const float* __restrict__ conv2_w, const float* __restrict__ conv2_b,
    const float* __restrict__ bn2_g, const float* __restrict__ bn2_b,
    const float* __restrict__ bn2_m, const float* __restrict__ bn2_v,
    const float* __restrict__ actor_w, const float* __restrict__ emb_w,
    const float* __restrict__ b_ih, const float* __restrict__ b_hh,
    float* __restrict__ ws)
{
  int i = blockIdx.x * 256 + threadIdx.x;
  if (i < 131072) {                      // W1T[c][o] = conv1_w[o][c]
    int c = i >> 8, o = i & 255;
    ws[WS_W1T + i] = conv1_w[o * 512 + c];
    return;
  }
  i -= 131072;
  if (i < 16384) {                       // W2T[c][o] = conv2_w[o][c]
    int c = i >> 6, o = i & 63;
    ws[WS_W2T + i] = conv2_w[o * 256 + c];
    return;
  }
  i -= 16384;
  if (i < 344064) {                      // APT[k][o], cont=[h|inp] -> xcat=[inp|h]
    int k = i >> 7, o = i & 127;
    int src = (k < DIN) ? (DH + k) : (k - DIN);
    ws[WS_APT + i] = actor_w[o * DCAT + src];
    return;
  }
  i -= 344064;
  if (i < 65536) {                       // EWT[j][v] = emb_w[v][j]
    int j = i >> 9, v = i & 511;
    ws[WS_EWT + i] = emb_w[v * 128 + j];
    return;
  }
  i -= 65536;
  if (i < 4096) { ws[WS_BSUM + i] = b_ih[i] + b_hh[i]; return; }
  i -= 4096;
  if (i < 256) {
    float a = bn1_g[i] / sqrtf(bn1_v[i] + 1e-5f);
    ws[WS_A1 + i] = a;
    ws[WS_B1 + i] = a * (conv1_b[i] - bn1_m[i]) + bn1_b[i];
    return;
  }
  i -= 256;
  if (i < 64) {
    float a = bn2_g[i] / sqrtf(bn2_v[i] + 1e-5f);
    ws[WS_A2 + i] = a;
    ws[WS_B2 + i] = a * (conv2_b[i] - bn2_m[i]) + bn2_b[i];
  }
}

// ---------------------------------------------------------------------------
__global__ __launch_bounds__(256) void k_init(
    const float* __restrict__ h0, const float* __restrict__ c0,
    const float* __restrict__ go, float* __restrict__ ws)
{
  int b = blockIdx.x, tid = threadIdx.x;
  if (tid < 128) ws[WS_XCAT + b * DCAT + 1536 + tid] = go[tid];
  for (int d = tid; d < 1024; d += 256) {
    ws[WS_XCAT + b * DCAT + 1664 + d] = h0[b * 1024 + d];
    ws[WS_CBUF + b * 1024 + d] = c0[b * 1024 + d];
  }
}

// ---------------------------------------------------------------------------
// visconv (r13 verbatim: LDS-staged Wc for 16x on-CU reuse)
__global__ __launch_bounds__(256) void k_visconv(
    const float* __restrict__ frames, float* __restrict__ ws)
{
  __shared__ float lds[10240];           // 40KB
  float* Xc  = lds;
  float* Wc  = lds + 2048;
  float* Y1c = lds;
  const int bt = blockIdx.x, tid = threadIdx.x;
  const int tn = tid & 15, tm = tid >> 4;
  const float* img = frames + (size_t)bt * 25088;
  const float* W1T = ws + WS_W1T;
  const float* W2T = ws + WS_W2T;

  float acc1[4][16];
  #pragma unroll
  for (int m = 0; m < 4; ++m)
    #pragma unroll
    for (int j = 0; j < 16; ++j) acc1[m][j] = 0.f;

  for (int i = tid; i < 2048; i += 256) Xc[i] = 0.f;
  __syncthreads();

  for (int ch = 0; ch < 16; ++ch) {
    for (int i4 = tid; i4 < 392; i4 += 256) {
      float4 v = *(const float4*)(img + ch * 1568 + (i4 << 2));
      int gi = i4 << 2;
      #pragma unroll
      for (int j = 0; j < 4; ++j) {
        int e = gi + j, c = e / 49, hw = e - c * 49;
        Xc[(c << 6) + hw] = (&v.x)[j];
      }
    }
    const float4* wsrc = (const float4*)(W1T + (ch << 13));
    for (int i = tid; i < 2048; i += 256) ((float4*)Wc)[i] = wsrc[i];
    __syncthreads();
    #pragma unroll 4
    for (int c = 0; c < 32; ++c) {
      const float4 a4 = *(const float4*)&Xc[(c << 6) + (tm << 2)];
      float a[4] = {a4.x, a4.y, a4.z, a4.w};
      const float* wr = &Wc[(c << 8) + (tn << 2)];
      #pragma unroll
      for (int ko = 0; ko < 4; ++ko) {
        const float4 b4 = *(const float4*)&wr[ko << 6];
        float bb[4] = {b4.x, b4.y, b4.z, b4.w};
        #pragma unroll
        for (int m = 0; m < 4; ++m)
          #pragma unroll
          for (int jo = 0; jo < 4; ++jo)
            acc1[m][(ko << 2) + jo] += a[m] * bb[jo];
      }
    }
    __syncthreads();
  }

  #pragma unroll
  for (int ko = 0; ko < 4; ++ko)
    #pragma unroll
    for (int jo = 0; jo < 4; ++jo) {
      const int o = (ko << 6) + (tn << 2) + jo;
      const float aa = ws[WS_A1 + o], bb = ws[WS_B1 + o];
      #pragma unroll
      for (int m = 0; m < 4; ++m)
        acc1[m][(ko << 2) + jo] = fmaxf(aa * acc1[m][(ko << 2) + jo] + bb, 0.f);
    }

  float acc2[4][4];
  #pragma unroll
  for (int m = 0; m < 4; ++m)
    #pragma unroll
    for (int j = 0; j < 4; ++j) acc2[m][j] = 0.f;
  for (int r = 0; r < 2; ++r) {
    __syncthreads();
    #pragma unroll
    for (int kh = 0; kh < 2; ++kh) {
      const int ko = (r << 1) + kh;
      #pragma unroll
      for (int jo = 0; jo < 4; ++jo) {
        const int row = (kh << 6) + (tn << 2) + jo;
        float4 v;
        v.x = acc1[0][(ko << 2) + jo]; v.y = acc1[1][(ko << 2) + jo];
        v.z = acc1[2][(ko << 2) + jo]; v.w = acc1[3][(ko << 2) + jo];
        *(float4*)&Y1c[row * 68 + (tm << 2)] = v;
      }
    }
    __syncthreads();
    #pragma unroll 4
    for (int c2l = 0; c2l < 128; ++c2l) {
      const float4 a4 = *(const float4*)&Y1c[c2l * 68 + (tm << 2)];
      float a[4] = {a4.x, a4.y, a4.z, a4.w};
      const float4 b4 = *(const float4*)&W2T[(((r << 7) + c2l) << 6) + (tn << 2)];
      float bb[4] = {b4.x, b4.y, b4.z, b4.w};
      #pragma unroll
      for (int m = 0; m < 4; ++m)
        #pragma unroll
        for (int jo = 0; jo < 4; ++jo)
          acc2[m][jo] += a[m] * bb[jo];
    }
  }

  float* y2f = ws + WS_Y2F + (size_t)bt * 3136;
  #pragma unroll
  for (int jo = 0; jo < 4; ++jo) {
    const int o2 = (tn << 2) + jo;
    const float aa = ws[WS_A2 + o2], bb = ws[WS_B2 + o2];
    #pragma unroll
    for (int m = 0; m < 4; ++m) {
      const int hw = (tm << 2) + m;
      if (hw < 49) y2f[o2 * 49 + hw] = fmaxf(aa * acc2[m][jo] + bb, 0.f);
    }
  }
}

// ---------------------------------------------------------------------------
// fc GEMM, 64x64 tiles, XCD-swizzled, float4 staging. grid (400, 2).
__global__ __launch_bounds__(256) void k_gemmfc(
    const float* __restrict__ A, const float* __restrict__ B,
    float* __restrict__ ws)
{
  __shared__ float As[32 * 68];
  __shared__ float Bs[32 * 68];
  const int tid = threadIdx.x;
  const int fid = blockIdx.x, bz = blockIdx.y;
  const int w = (fid & 7) * 50 + (fid >> 3);
  const int bm = w >> 3, bn = w & 7;
  const int tm = tid >> 4, tn = tid & 15;
  float acc[4][4];
  #pragma unroll
  for (int i = 0; i < 4; ++i)
    #pragma unroll
    for (int j = 0; j < 4; ++j) acc[i][j] = 0.f;

  const int kbase0 = bz * 1568;
  for (int kk = 0; kk < 1568; kk += 32) {
    const int kb = kbase0 + kk;
    #pragma unroll
    for (int i = 0; i < 2; ++i) {
      const int e = tid + i * 256;
      const int r = e >> 3, kq = e & 7;
      const float4 av = *(const float4*)&A[(size_t)(bm * 64 + r) * 3136 + kb + kq * 4];
      As[(kq * 4 + 0) * 68 + r] = av.x;
      As[(kq * 4 + 1) * 68 + r] = av.y;
      As[(kq * 4 + 2) * 68 + r] = av.z;
      As[(kq * 4 + 3) * 68 + r] = av.w;
      const float4 bv = *(const float4*)&B[(size_t)(bn * 64 + r) * 3136 + kb + kq * 4];
      Bs[(kq * 4 + 0) * 68 + r] = bv.x;
      Bs[(kq * 4 + 1) * 68 + r] = bv.y;
      Bs[(kq * 4 + 2) * 68 + r] = bv.z;
      Bs[(kq * 4 + 3) * 68 + r] = bv.w;
    }
    __syncthreads();
    #pragma unroll
    for (int k = 0; k < 32; ++k) {
      const float4 a4 = *(const float4*)&As[k * 68 + tm * 4];
      const float4 b4 = *(const float4*)&Bs[k * 68 + tn * 4];
      acc[0][0] += a4.x*b4.x; acc[0][1] += a4.x*b4.y; acc[0][2] += a4.x*b4.z; acc[0][3] += a4.x*b4.w;
      acc[1][0] += a4.y*b4.x; acc[1][1] += a4.y*b4.y; acc[1][2] += a4.y*b4.z; acc[1][3] += a4.y*b4.w;
      acc[2][0] += a4.z*b4.x; acc[2][1] += a4.z*b4.y; acc[2][2] += a4.z*b4.z; acc[2][3] += a4.z*b4.w;
      acc[3][0] += a4.w*b4.x; acc[3][1] += a4.w*b4.y; acc[3][2] += a4.w*b4.z; acc[3][3] += a4.w*b4.w;
    }
    __syncthreads();
  }
  float* Cz = ws + (bz ? WS_QPART : WS_VIS);
  #pragma unroll
  for (int i = 0; i < 4; ++i) {
    const int row = bm * 64 + tm * 4 + i;
    const int col0 = bn * 64 + tn * 4;
    float4 v;
    v.x = acc[i][0]; v.y = acc[i][1]; v.z = acc[i][2]; v.w = acc[i][3];
    *(float4*)&Cz[(size_t)row * 512 + col0] = v;
  }
}

// fc combine: VIS = (z0 partial in VIS) + (z1 partial in QPART) + fc_b
__global__ __launch_bounds__(256) void k_fccomb(
    const float* __restrict__ fc_b, float* __restrict__ ws)
{
  const int id = blockIdx.x * 256 + threadIdx.x;
  ws[WS_VIS + id] += ws[WS_QPART + id] + fc_b[id & 511];
}

// ---------------------------------------------------------------------------
// qgemm: 128x64 tile GEMM (h @ hfc_w^T), K=1024 split 8 -> QPART partials.
__global__ __launch_bounds__(256) void k_gemm2(
    const float* __restrict__ A, int lda,
    const float* __restrict__ B, int ldb,
    float* __restrict__ C, int ldc,
    int Kz, long strideCz)
{
  __shared__ float As[32 * 133];
  __shared__ float Bs[32 * 69];
  const int tid = threadIdx.x;
  const int bm = blockIdx.x, bn = blockIdx.y, bz = blockIdx.z;
  const int tm = tid >> 4, tn = tid & 15;
  float acc[8][4];
  #pragma unroll
  for (int i = 0; i < 8; ++i)
    #pragma unroll
    for (int j = 0; j < 4; ++j) acc[i][j] = 0.f;

  const int kbase0 = bz * Kz;
  for (int kk = 0; kk < Kz; kk += 32) {
    const int kb = kbase0 + kk;
    #pragma unroll
    for (int i = 0; i < 16; ++i) {
      const int e = tid + i * 256;
      const int k = e & 31, m = e >> 5;
      As[k * 133 + m] = A[(size_t)(bm * 128 + m) * lda + kb + k];
    }
    #pragma unroll
    for (int i = 0; i < 8; ++i) {
      const int e = tid + i * 256;
      const int k = e & 31, n = e >> 5;
      Bs[k * 69 + n] = B[(size_t)(bn * 64 + n) * ldb + kb + k];
    }
    __syncthreads();
    #pragma unroll
    for (int k = 0; k < 32; ++k) {
      const float4 a0 = *(const float4*)&As[k * 133 + tm * 8];
      const float4 a1 = *(const float4*)&As[k * 133 + tm * 8 + 4];
      const float4 b4 = *(const float4*)&Bs[k * 69 + tn * 4];
      const float av[8] = {a0.x, a0.y, a0.z, a0.w, a1.x, a1.y, a1.z, a1.w};
      const float bv[4] = {b4.x, b4.y, b4.z, b4.w};
      #pragma unroll
      for (int i = 0; i < 8; ++i)
        #pragma unroll
        for (int j = 0; j < 4; ++j)
          acc[i][j] += av[i] * bv[j];
    }
    __syncthreads();
  }
  float* Cz = C + (long)bz * strideCz;
  #pragma unroll
  for (int i = 0; i < 8; ++i) {
    const int row = bm * 128 + tm * 8 + i;
    const int col0 = bn * 64 + tn * 4;
    float4 v;
    v.x = acc[i][0]; v.y = acc[i][1]; v.z = acc[i][2]; v.w = acc[i][3];
    *(float4*)&Cz[(size_t)row * ldc + col0] = v;
  }
}

// ---------------------------------------------------------------------------
// Flash attention over one 64-row L-segment. grid (8 seg, 128 b), 512 thr.
// 3-set explicit register prefetch (A/B/C), fully unrolled 8-row loop.
__global__ __launch_bounds__(512) void k_attn(
    const float* __restrict__ enc, const float* __restrict__ hfc_b,
    float* __restrict__ ws)
{
  __shared__ float q_lds[1024];
  __shared__ float raw_lds[64];
  __shared__ float accw[8][1024];
  __shared__ float m_lds[8];
  __shared__ float z_lds[8];
  const int seg = blockIdx.x, b = blockIdx.y, tid = threadIdx.x;
  const float* qpart = ws + WS_QPART;
  for (int d = tid; d < 1024; d += 512) {
    float s = hfc_b[d];
    #pragma unroll
    for (int sp = 0; sp < 8; ++sp) s += qpart[sp * 131072 + b * 1024 + d];
    q_lds[d] = s;
  }
  __syncthreads();
  const int lane = tid & 63, wv = tid >> 6;
  const float4 q0 = *(const float4*)&q_lds[lane * 4];
  const float4 q1 = *(const float4*)&q_lds[lane * 4 + 256];
  const float4 q2 = *(const float4*)&q_lds[lane * 4 + 512];
  const float4 q3 = *(const float4*)&q_lds[lane * 4 + 768];
  const float* row = enc + (size_t)b * (NL * DH) + (size_t)seg * 64 * DH + lane * 4;
  float m = -INFINITY, z = 0.f;
  float4 ac0 = {0,0,0,0}, ac1 = {0,0,0,0}, ac2 = {0,0,0,0}, ac3 = {0,0,0,0};

  #define LOADSET(S, r) \
    S##0 = *(const float4*)&row[(wv + ((r) << 3)) * 1024]; \
    S##1 = *(const float4*)&row[(wv + ((r) << 3)) * 1024 + 256]; \
    S##2 = *(const float4*)&row[(wv + ((r) << 3)) * 1024 + 512]; \
    S##3 = *(const float4*)&row[(wv + ((r) << 3)) * 1024 + 768];

  float4 A0, A1, A2, A3, B0, B1, B2, B3, C0, C1, C2, C3;
  LOADSET(A, 0)
  LOADSET(B, 1)
  LOADSET(C, 2)

  auto body = [&](int r, const float4& c0_, const float4& c1_,
                  const float4& c2_, const float4& c3_) {
    const int l = wv + (r << 3);
    float d = c0_.x*q0.x + c0_.y*q0.y + c0_.z*q0.z + c0_.w*q0.w;
    d += c1_.x*q1.x + c1_.y*q1.y + c1_.z*q1.z + c1_.w*q1.w;
    d += c2_.x*q2.x + c2_.y*q2.y + c2_.z*q2.z + c2_.w*q2.w;
    d += c3_.x*q3.x + c3_.y*q3.y + c3_.z*q3.z + c3_.w*q3.w;
    #pragma unroll
    for (int off = 32; off > 0; off >>= 1) d += __shfl_xor(d, off, 64);
    if (lane == 0) raw_lds[l] = d;
    const float mn = fmaxf(m, d);
    const float sc = expf(m - mn);
    const float p  = expf(d - mn);
    z = z * sc + p;
    ac0.x = ac0.x*sc + p*c0_.x; ac0.y = ac0.y*sc + p*c0_.y; ac0.z = ac0.z*sc + p*c0_.z; ac0.w = ac0.w*sc + p*c0_.w;
    ac1.x = ac1.x*sc + p*c1_.x; ac1.y = ac1.y*sc + p*c1_.y; ac1.z = ac1.z*sc + p*c1_.z; ac1.w = ac1.w*sc + p*c1_.w;
    ac2.x = ac2.x*sc + p*c2_.x; ac2.y = ac2.y*sc + p*c2_.y; ac2.z = ac2.z*sc + p*c2_.z; ac2.w = ac2.w*sc + p*c2_.w;
    ac3.x = ac3.x*sc + p*c3_.x; ac3.y = ac3.y*sc + p*c3_.y; ac3.z = ac3.z*sc + p*c3_.z; ac3.w = ac3.w*sc + p*c3_.w;
    m = mn;
  };

  body(0, A0, A1, A2, A3); LOADSET(A, 3)
  body(1, B0, B1, B2, B3); LOADSET(B, 4)
  body(2, C0, C1, C2, C3); LOADSET(C, 5)
  body(3, A0, A1, A2, A3); LOADSET(A, 6)
  body(4, B0, B1, B2, B3); LOADSET(B, 7)
  body(5, C0, C1, C2, C3);
  body(6, A0, A1, A2, A3);
  body(7, B0, B1, B2, B3);
  #undef LOADSET

  *(float4*)&accw[wv][lane * 4      ] = ac0;
  *(float4*)&accw[wv][lane * 4 + 256] = ac1;
  *(float4*)&accw[wv][lane * 4 + 512] = ac2;
  *(float4*)&accw[wv][lane * 4 + 768] = ac3;
  if (lane == 0) { m_lds[wv] = m; z_lds[wv] = z; }
  __syncthreads();
  float M = m_lds[0];
  #pragma unroll
  for (int s = 1; s < 8; ++s) M = fmaxf(M, m_lds[s]);
  float ef[8];
  #pragma unroll
  for (int s = 0; s < 8; ++s) ef[s] = expf(m_lds[s] - M);
  float Z = 0.f;
  #pragma unroll
  for (int s = 0; s < 8; ++s) Z += ef[s] * z_lds[s];
  float* att = ws + WS_ATT + ((size_t)b * NSEG + seg) * 1032;
  for (int d = tid; d < 1024; d += 512) {
    float s = 0.f;
    #pragma unroll
    for (int w8 = 0; w8 < 8; ++w8) s += ef[w8] * accw[w8][d];
    att[d] = s;
  }
  if (tid == 0) { att[1024] = M; att[1025] = Z; }
  if (tid < 64) ws[WS_ATTRAW + b * 512 + seg * 64 + tid] = raw_lds[tid];
}

// ---------------------------------------------------------------------------
// Combine 8-seg partials ONCE per (b). 128 blocks x 256 thr.
__global__ __launch_bounds__(256) void k_comb(
    float* __restrict__ ws, float* __restrict__ out, int t)
{
  const int b = blockIdx.x, tid = threadIdx.x;
  const float* att = ws + WS_ATT + (size_t)b * NSEG * 1032;
  float* xcat = ws + WS_XCAT + (size_t)b * DCAT;
  float ms[NSEG], zs[NSEG];
  #pragma unroll
  for (int s = 0; s < NSEG; ++s) { ms[s] = att[s * 1032 + 1024]; zs[s] = att[s * 1032 + 1025]; }
  float M = ms[0];
  #pragma unroll
  for (int s = 1; s < NSEG; ++s) M = fmaxf(M, ms[s]);
  float ef[NSEG], Z = 0.f;
  #pragma unroll
  for (int s = 0; s < NSEG; ++s) { ef[s] = expf(ms[s] - M); Z += ef[s] * zs[s]; }
  const float inv = 1.f / Z;
  for (int i = tid; i < 512; i += 256)
    xcat[i] = ws[WS_VIS + ((size_t)b * NT + t) * DF + i];
  for (int d = tid; d < 1024; d += 256) {
    float w = 0.f;
    #pragma unroll
    for (int s = 0; s < NSEG; ++s) w += ef[s] * att[s * 1032 + d];
    xcat[512 + d] = w * inv;
  }
  for (int l = tid; l < 512; l += 256)
    out[SC_OFF + ((size_t)b * NT + t) * NL + l] =
        expf(ws[WS_ATTRAW + b * 512 + l] - M) * inv;
}

// ---------------------------------------------------------------------------
// Gates: gpart[bz] = xcat[:, bz*224:(bz+1)*224] @ W^T slice.
// grid (64 bn, 12 bz). 128x64 tile, 8x4/thread, BK=32.
__global__ __launch_bounds__(256) void k_gates(
    const float* __restrict__ w_ih, const float* __restrict__ w_hh,
    float* __restrict__ ws)
{
  __shared__ float As[32 * 132];
  __shared__ float Bs[32 * 68];
  const int tid = threadIdx.x;
  const int bn = blockIdx.x, bz = blockIdx.y;
  const int tm = tid >> 4, tn = tid & 15;
  float acc[8][4];
  #pragma unroll
  for (int i = 0; i < 8; ++i)
    #pragma unroll
    for (int j = 0; j < 4; ++j) acc[i][j] = 0.f;

  const float* xc = ws + WS_XCAT;
  for (int kk = 0; kk < 224; kk += 32) {
    const int kb = bz * 224 + kk;
    #pragma unroll
    for (int i = 0; i < 4; ++i) {
      const int e = tid + i * 256;
      const int r = e >> 3, kq = e & 7;
      const float4 av = *(const float4*)&xc[(size_t)r * DCAT + kb + kq * 4];
      As[(kq * 4 + 0) * 132 + r] = av.x;
      As[(kq * 4 + 1) * 132 + r] = av.y;
      As[(kq * 4 + 2) * 132 + r] = av.z;
      As[(kq * 4 + 3) * 132 + r] = av.w;
    }
    #pragma unroll
    for (int i = 0; i < 2; ++i) {
      const int e = tid + i * 256;
      const int n = e >> 3, kq = e & 7;
      const int g = bn * 64 + n;
      const float4 bv = (kb < DIN)
          ? *(const float4*)&w_ih[(size_t)g * DIN + kb + kq * 4]
          : *(const float4*)&w_hh[(size_t)g * DH + (kb - DIN) + kq * 4];
      Bs[(kq * 4 + 0) * 68 + n] = bv.x;
      Bs[(kq * 4 + 1) * 68 + n] = bv.y;
      Bs[(kq * 4 + 2) * 68 + n] = bv.z;
      Bs[(kq * 4 + 3) * 68 + n] = bv.w;
    }
    __syncthreads();
    #pragma unroll
    for (int k = 0; k < 32; ++k) {
      const float4 a0 = *(const float4*)&As[k * 132 + tm * 8];
      const float4 a1 = *(const float4*)&As[k * 132 + tm * 8 + 4];
      const float4 b4 = *(const float4*)&Bs[k * 68 + tn * 4];
      const float av[8] = {a0.x, a0.y, a0.z, a0.w, a1.x, a1.y, a1.z, a1.w};
      const float bv[4] = {b4.x, b4.y, b4.z, b4.w};
      #pragma unroll
      for (int i = 0; i < 8; ++i)
        #pragma unroll
        for (int j = 0; j < 4; ++j)
          acc[i][j] += av[i] * bv[j];
    }
    __syncthreads();
  }
  float* Cz = ws + WS_GPART + (size_t)bz * 524288;
  #pragma unroll
  for (int i = 0; i < 8; ++i) {
    const int b = tm * 8 + i;
    const int col0 = bn * 64 + tn * 4;
    float4 v;
    v.x = acc[i][0]; v.y = acc[i][1]; v.z = acc[i][2]; v.w = acc[i][3];
    *(float4*)&Cz[(size_t)b * 4096 + col0] = v;
  }
}

// ---------------------------------------------------------------------------
// Fused LSTM pointwise + actor + argmax + embed feedback. 128 blocks x 512 thr.
__global__ __launch_bounds__(512) void k_lstmactor(
    const float* __restrict__ emb_w, const float* __restrict__ actor_b,
    float* __restrict__ ws, float* __restrict__ out, int t, int last)
{
  __shared__ float xl[DCAT];
  __shared__ float ph[512];
  __shared__ float ae[128];
  __shared__ float bv[512];
  __shared__ int   bi[512];
  const int b = blockIdx.x, tid = threadIdx.x;
  float* xcat = ws + WS_XCAT + (size_t)b * DCAT;

  for (int i = tid; i < 416; i += 512)
    ((float4*)xl)[i] = ((const float4*)xcat)[i];

  const float* gpart = ws + WS_GPART;
  const float* bsum = ws + WS_BSUM;
  for (int j = tid; j < 1024; j += 512) {
    float g[4];
    #pragma unroll
    for (int gi = 0; gi < 4; ++gi) {
      const int x = gi * 1024 + j;
      float s = bsum[x];
      #pragma unroll
      for (int sp = 0; sp < NGZ; ++sp) s += gpart[(size_t)sp * 524288 + b * 4096 + x];
      g[gi] = s;
    }
    const float ii = 1.f / (1.f + expf(-g[0]));
    const float ff = 1.f / (1.f + expf(-g[1]));
    const float gg = tanhf(g[2]);
    const float oo = 1.f / (1.f + expf(-g[3]));
    const float c = ff * ws[WS_CBUF + b * 1024 + j] + ii * gg;
    const float h = oo * tanhf(c);
    ws[WS_CBUF + b * 1024 + j] = c;
    xl[1664 + j] = h;
    xcat[1664 + j] = h;
    if (last) { out[H_OFF + b * 1024 + j] = h; out[C_OFF + b * 1024 + j] = c; }
  }
  __syncthreads();

  {
    const int o = tid & 127;
    const int k0 = (tid >> 7) * 672;
    const float* APT = ws + WS_APT;
    float s = 0.f;
    #pragma unroll 8
    for (int k = k0; k < k0 + 672; ++k) s += xl[k] * APT[k * 128 + o];
    ph[tid] = s;
  }
  __syncthreads();
  if (tid < 128)
    ae[tid] = ph[tid] + ph[tid + 128] + ph[tid + 256] + ph[tid + 384] + actor_b[tid];
  __syncthreads();

  const float* EWT = ws + WS_EWT;
  float s = 0.f;
  #pragma unroll 8
  for (int j = 0; j < 128; ++j) s += ae[j] * EWT[j * 512 + tid];
  out[ACT_OFF + ((size_t)b * NT + t) * NV + tid] = s;
  bv[tid] = s; bi[tid] = tid;
  __syncthreads();
  for (int s2 = 256; s2 > 0; s2 >>= 1) {
    if (tid < s2) {
      float ov = bv[tid + s2]; int oi = bi[tid + s2];
      if (ov > bv[tid] || (ov == bv[tid] && oi < bi[tid])) { bv[tid] = ov; bi[tid] = oi; }
    }
    __syncthreads();
  }
  const int am = bi[0];
  if (tid < 128) xcat[1536 + tid] = emb_w[am * 128 + tid];
}

// ---------------------------------------------------------------------------
extern "C" void kernel_launch(void* const* d_in, const int* in_sizes, int n_in,
                              void* d_out, int out_size, void* d_ws, size_t ws_size,
                              hipStream_t stream)
{
  const float* enc     = (const float*)d_in[0];
  const float* frames  = (const float*)d_in[1];
  const float* h0      = (const float*)d_in[2];
  const float* c0      = (const float*)d_in[3];
  const float* emb_w   = (const float*)d_in[5];
  const float* go      = (const float*)d_in[6];
  const float* conv1_w = (const float*)d_in[7];
  const float* conv1_b = (const float*)d_in[8];
  const float* bn1_g   = (const float*)d_in[9];
  const float* bn1_b   = (const float*)d_in[10];
  const float* bn1_m   = (const float*)d_in[11];
  const float* bn1_v   = (const float*)d_in[12];
  const float* conv2_w = (const float*)d_in[13];
  const float* conv2_b = (const float*)d_in[14];
  const float* bn2_g   = (const float*)d_in[15];
  const float* bn2_b   = (const float*)d_in[16];
  const float* bn2_m   = (const float*)d_in[17];
  const float* bn2_v   = (const float*)d_in[18];
  const float* fc_w    = (const float*)d_in[19];
  const float* fc_b    = (const float*)d_in[20];
  const float* hfc_w   = (const float*)d_in[21];
  const float* hfc_b   = (const float*)d_in[22];
  const float* w_ih    = (const float*)d_in[23];
  const float* b_ih    = (const float*)d_in[24];
  const float* w_hh    = (const float*)d_in[25];
  const float* b_hh    = (const float*)d_in[26];
  const float* actor_w = (const float*)d_in[27];
  const float* actor_b = (const float*)d_in[28];
  float* out = (float*)d_out;
  float* ws  = (float*)d_ws;

  k_prep<<<2194, 256, 0, stream>>>(conv1_w, conv1_b, bn1_g, bn1_b, bn1_m, bn1_v,
      conv2_w, conv2_b, bn2_g, bn2_b, bn2_m, bn2_v, actor_w, emb_w, b_ih, b_hh, ws);
  k_init<<<128, 256, 0, stream>>>(h0, c0, go, ws);
  k_visconv<<<3200, 256, 0, stream>>>(frames, ws);
  k_gemmfc<<<dim3(400, 2), 256, 0, stream>>>(ws + WS_Y2F, fc_w, ws);
  k_fccomb<<<6400, 256, 0, stream>>>(fc_b, ws);

  for (int t = 0; t < NT; ++t) {
    k_gemm2<<<dim3(1, 16, 8), 256, 0, stream>>>(ws + WS_XCAT + 1664, DCAT,
        hfc_w, 1024, ws + WS_QPART, 1024, 128, 131072);
    k_attn<<<dim3(NSEG, 128), 512, 0, stream>>>(enc, hfc_b, ws);
    k_comb<<<128, 256, 0, stream>>>(ws, out, t);
    k_gates<<<dim3(64, NGZ), 256, 0, stream>>>(w_ih, w_hh, ws);
    k_lstmactor<<<128, 512, 0, stream>>>(emb_w, actor_b, ws, out, t,
                                         t == NT - 1 ? 1 : 0);
  }
}